// Round 1
// baseline (137.232 us; speedup 1.0000x reference)
//
#include <hip/hip_runtime.h>
#include <hip/hip_bf16.h>

typedef __attribute__((ext_vector_type(8))) short short8;
typedef __attribute__((ext_vector_type(4))) float f32x4;

#define DIM_D 256
#define DIM_O 256
#define DIM_K 8
#define BM 128
#define DCHUNK 16
#define NCHUNK (DIM_D / DCHUNK)   // 16

__device__ __forceinline__ unsigned short f2bf(float f) {
    union { float f; unsigned int u; } v; v.f = f;
    unsigned int u = v.u;
    u += 0x7fffu + ((u >> 16) & 1u);   // round-to-nearest-even
    return (unsigned short)(u >> 16);
}

// Pack cheby_coeffs (O, D, K) f32 -> W_packed bf16 in MFMA B-fragment order:
// wp[ksg][F][lane][j] = c[o = 16F + (lane&15)][d = ksg*4 + (lane>>4)][k = j]
// so a wave's lane can load its 16B B-fragment with one coalesced dwordx4.
__global__ void pack_w_kernel(const float* __restrict__ coeffs,
                              unsigned short* __restrict__ wp) {
    int e = blockIdx.x * 256 + threadIdx.x;      // 0 .. 524287
    int j   = e & 7;
    int l   = (e >> 3) & 63;
    int F   = (e >> 9) & 15;
    int ksg = e >> 13;                           // 0..63
    int o = F * 16 + (l & 15);
    int d = ksg * 4 + (l >> 4);
    wp[e] = f2bf(coeffs[(size_t)(o * DIM_D + d) * DIM_K + j]);
}

__global__ __launch_bounds__(256) void cfkan_kernel(
    const float* __restrict__ x,
    const unsigned short* __restrict__ wp,
    const float* __restrict__ bias,
    float* __restrict__ y)
{
    // A tile: [row][16 slots of 16B] ; slot = d_local ^ (row&15)  (XOR swizzle,
    // makes both the b128 writes and the per-fragment b128 reads ~conflict-free)
    __shared__ unsigned short Abuf[BM][16 * 8];

    const int t = threadIdx.x;
    const int w = t >> 6;            // wave 0..3 -> output cols [64w, 64w+64)
    const int l = t & 63;
    const int row0 = blockIdx.x * BM;

    f32x4 acc[8][4];
    #pragma unroll
    for (int r = 0; r < 8; ++r)
        #pragma unroll
        for (int f = 0; f < 4; ++f)
            acc[r][f] = (f32x4){0.f, 0.f, 0.f, 0.f};

    const int lrow  = t >> 1;        // 0..127 (row this thread stages)
    const int dpart = (t & 1) * 8;   // which 8 of the 16 chunk-d's

    for (int c = 0; c < NCHUNK; ++c) {
        const int d0 = c * DCHUNK;

        // ---- stage phase: load x, tanh, Chebyshev recurrence, pack to LDS ----
        const float* xp = x + (size_t)(row0 + lrow) * DIM_D + d0 + dpart;
        float4 v0 = *(const float4*)xp;
        float4 v1 = *(const float4*)(xp + 4);
        float xv[8] = {v0.x, v0.y, v0.z, v0.w, v1.x, v1.y, v1.z, v1.w};
        #pragma unroll
        for (int i = 0; i < 8; ++i) {
            float xc = fminf(fmaxf(xv[i], -15.f), 15.f);
            float e2 = __expf(2.f * xc);
            float xt = (e2 - 1.f) / (e2 + 1.f);   // tanh
            float T0 = 1.f;
            float T1 = xt;
            float tx = 2.f * xt;
            float T2 = tx * T1 - T0;
            float T3 = tx * T2 - T1;
            float T4 = tx * T3 - T2;
            float T5 = tx * T4 - T3;
            float T6 = tx * T5 - T4;
            float T7 = tx * T6 - T5;
            short8 tv;
            tv[0] = (short)f2bf(T0);
            tv[1] = (short)f2bf(T1);
            tv[2] = (short)f2bf(T2);
            tv[3] = (short)f2bf(T3);
            tv[4] = (short)f2bf(T4);
            tv[5] = (short)f2bf(T5);
            tv[6] = (short)f2bf(T6);
            tv[7] = (short)f2bf(T7);
            int dl = dpart + i;
            int slot = dl ^ (lrow & 15);
            *(short8*)&Abuf[lrow][slot * 8] = tv;
        }
        __syncthreads();

        // ---- MFMA phase: 4 k-steps of 32 (= 4 d each) ----
        #pragma unroll
        for (int ks = 0; ks < 4; ++ks) {
            const int ksg = c * 4 + ks;
            short8 b[4];
            #pragma unroll
            for (int f = 0; f < 4; ++f)
                b[f] = *((const short8*)wp + ((ksg * 16 + w * 4 + f) * 64 + l));
            const int slot = (ks * 4 + (l >> 4)) ^ (l & 15);
            #pragma unroll
            for (int r = 0; r < 8; ++r) {
                short8 a = *(const short8*)&Abuf[r * 16 + (l & 15)][slot * 8];
                #pragma unroll
                for (int f = 0; f < 4; ++f)
                    acc[r][f] = __builtin_amdgcn_mfma_f32_16x16x32_bf16(
                        a, b[f], acc[r][f], 0, 0, 0);
            }
        }
        __syncthreads();
    }

    // ---- epilogue: add bias, store f32 ----
    #pragma unroll
    for (int f = 0; f < 4; ++f) {
        const int col = w * 64 + f * 16 + (l & 15);
        const float bv = bias[col];
        #pragma unroll
        for (int r = 0; r < 8; ++r) {
            const int grow = row0 + r * 16 + (l >> 4) * 4;
            #pragma unroll
            for (int q = 0; q < 4; ++q)
                y[(size_t)(grow + q) * DIM_O + col] = acc[r][f][q] + bv;
        }
    }
}

extern "C" void kernel_launch(void* const* d_in, const int* in_sizes, int n_in,
                              void* d_out, int out_size, void* d_ws, size_t ws_size,
                              hipStream_t stream) {
    const float* x      = (const float*)d_in[0];
    const float* coeffs = (const float*)d_in[1];
    const float* bias   = (const float*)d_in[2];
    float* y = (float*)d_out;
    unsigned short* wp = (unsigned short*)d_ws;   // 2048*256 bf16 = 1 MB

    const int n_tokens = in_sizes[0] / DIM_D;     // 65536

    pack_w_kernel<<<(DIM_O * DIM_D * DIM_K) / 256, 256, 0, stream>>>(coeffs, wp);
    cfkan_kernel<<<n_tokens / BM, 256, 0, stream>>>(x, wp, bias, y);
}

// Round 2
// 80.704 us; speedup vs baseline: 1.7004x; 1.7004x over previous
//
#include <hip/hip_runtime.h>
#include <hip/hip_bf16.h>

typedef __attribute__((ext_vector_type(8))) short short8;
typedef __attribute__((ext_vector_type(4))) float f32x4;

#define DIM_D 256
#define DIM_O 256
#define DIM_K 8
#define BM 128
#define DCHUNK 16
#define NCHUNK (DIM_D / DCHUNK)   // 16

__device__ __forceinline__ unsigned short f2bf(float f) {
    union { float f; unsigned int u; } v; v.f = f;
    unsigned int u = v.u;
    u += 0x7fffu + ((u >> 16) & 1u);   // round-to-nearest-even
    return (unsigned short)(u >> 16);
}

// Pack cheby_coeffs (O, D, K) f32 -> W_packed bf16 in MFMA B-fragment order:
// wp[ksg][F][lane][j] = c[o = 16F + (lane&15)][d = ksg*4 + (lane>>4)][k = j]
__global__ void pack_w_kernel(const float* __restrict__ coeffs,
                              unsigned short* __restrict__ wp) {
    int e = blockIdx.x * 256 + threadIdx.x;      // 0 .. 524287
    int j   = e & 7;
    int l   = (e >> 3) & 63;
    int F   = (e >> 9) & 15;
    int ksg = e >> 13;                           // 0..63
    int o = F * 16 + (l & 15);
    int d = ksg * 4 + (l >> 4);
    wp[e] = f2bf(coeffs[(size_t)(o * DIM_D + d) * DIM_K + j]);
}

// tanh + Chebyshev recurrence + bf16 pack + swizzled LDS write (8 elems)
__device__ __forceinline__ void cheb_pack(const float xv[8],
                                          unsigned short* dst_row,
                                          int lrow, int dpart) {
    #pragma unroll
    for (int i = 0; i < 8; ++i) {
        float xc = fminf(fmaxf(xv[i], -15.f), 15.f);
        float e2 = __expf(2.f * xc);
        float xt = (e2 - 1.f) * __builtin_amdgcn_rcpf(e2 + 1.f);  // tanh
        float T0 = 1.f;
        float T1 = xt;
        float tx = 2.f * xt;
        float T2 = tx * T1 - T0;
        float T3 = tx * T2 - T1;
        float T4 = tx * T3 - T2;
        float T5 = tx * T4 - T3;
        float T6 = tx * T5 - T4;
        float T7 = tx * T6 - T5;
        short8 tv;
        tv[0] = (short)f2bf(T0);
        tv[1] = (short)f2bf(T1);
        tv[2] = (short)f2bf(T2);
        tv[3] = (short)f2bf(T3);
        tv[4] = (short)f2bf(T4);
        tv[5] = (short)f2bf(T5);
        tv[6] = (short)f2bf(T6);
        tv[7] = (short)f2bf(T7);
        int slot = (dpart + i) ^ (lrow & 15);
        *(short8*)(dst_row + slot * 8) = tv;
    }
}

// one chunk's MFMA work: 4 k-steps (K=32 each), B frags straight from L2
__device__ __forceinline__ void mfma_chunk(const unsigned short (*A)[16 * 8],
                                           const short8* __restrict__ wp8,
                                           int c, int w, int l,
                                           f32x4 acc[8][4]) {
    #pragma unroll
    for (int ks = 0; ks < 4; ++ks) {
        const int ksg = c * 4 + ks;
        short8 b[4];
        #pragma unroll
        for (int f = 0; f < 4; ++f)
            b[f] = wp8[(ksg * 16 + w * 4 + f) * 64 + l];
        const int slot = (ks * 4 + (l >> 4)) ^ (l & 15);
        #pragma unroll
        for (int r = 0; r < 8; ++r) {
            short8 a = *(const short8*)(&A[r * 16 + (l & 15)][0] + slot * 8);
            #pragma unroll
            for (int f = 0; f < 4; ++f)
                acc[r][f] = __builtin_amdgcn_mfma_f32_16x16x32_bf16(
                    a, b[f], acc[r][f], 0, 0, 0);
        }
    }
}

__global__ __launch_bounds__(256, 2) void cfkan_kernel(
    const float* __restrict__ x,
    const unsigned short* __restrict__ wp,
    const float* __restrict__ bias,
    float* __restrict__ y)
{
    // double-buffered A tile, XOR-swizzled slots (slot = d ^ (row&15))
    __shared__ unsigned short Abuf[2][BM][16 * 8];

    const int t = threadIdx.x;
    const int w = t >> 6;            // wave 0..3 -> output cols [64w, 64w+64)
    const int l = t & 63;
    const int row0 = blockIdx.x * BM;
    const short8* wp8 = (const short8*)wp;

    f32x4 acc[8][4];
    #pragma unroll
    for (int r = 0; r < 8; ++r)
        #pragma unroll
        for (int f = 0; f < 4; ++f)
            acc[r][f] = (f32x4){0.f, 0.f, 0.f, 0.f};

    const int lrow  = t >> 1;        // 0..127 (row this thread stages)
    const int dpart = (t & 1) * 8;   // which 8 of the 16 chunk-d's

    // ---- prologue: stage chunk 0 into buf 0 ----
    {
        const float* xp = x + (size_t)(row0 + lrow) * DIM_D + dpart;
        float4 v0 = *(const float4*)xp;
        float4 v1 = *(const float4*)(xp + 4);
        float xv[8] = {v0.x, v0.y, v0.z, v0.w, v1.x, v1.y, v1.z, v1.w};
        cheb_pack(xv, &Abuf[0][lrow][0], lrow, dpart);
    }
    __syncthreads();

    // ---- main loop: one barrier per chunk; stage c+1 overlaps MFMA c ----
    #pragma unroll 1
    for (int c = 0; c < NCHUNK - 1; ++c) {
        const int buf = c & 1;
        // issue next chunk's x loads early (latency hides under MFMA)
        const float* xp = x + (size_t)(row0 + lrow) * DIM_D
                            + (c + 1) * DCHUNK + dpart;
        float4 v0 = *(const float4*)xp;
        float4 v1 = *(const float4*)(xp + 4);

        __builtin_amdgcn_s_setprio(1);
        mfma_chunk(Abuf[buf], wp8, c, w, l, acc);
        __builtin_amdgcn_s_setprio(0);

        float xv[8] = {v0.x, v0.y, v0.z, v0.w, v1.x, v1.y, v1.z, v1.w};
        cheb_pack(xv, &Abuf[buf ^ 1][lrow][0], lrow, dpart);
        __syncthreads();
    }
    __builtin_amdgcn_s_setprio(1);
    mfma_chunk(Abuf[(NCHUNK - 1) & 1], wp8, NCHUNK - 1, w, l, acc);
    __builtin_amdgcn_s_setprio(0);

    // ---- epilogue: add bias, store f32 ----
    #pragma unroll
    for (int f = 0; f < 4; ++f) {
        const int col = w * 64 + f * 16 + (l & 15);
        const float bv = bias[col];
        #pragma unroll
        for (int r = 0; r < 8; ++r) {
            const int grow = row0 + r * 16 + (l >> 4) * 4;
            #pragma unroll
            for (int q = 0; q < 4; ++q)
                y[(size_t)(grow + q) * DIM_O + col] = acc[r][f][q] + bv;
        }
    }
}

extern "C" void kernel_launch(void* const* d_in, const int* in_sizes, int n_in,
                              void* d_out, int out_size, void* d_ws, size_t ws_size,
                              hipStream_t stream) {
    const float* x      = (const float*)d_in[0];
    const float* coeffs = (const float*)d_in[1];
    const float* bias   = (const float*)d_in[2];
    float* y = (float*)d_out;
    unsigned short* wp = (unsigned short*)d_ws;   // 2048*256 bf16 = 1 MB

    const int n_tokens = in_sizes[0] / DIM_D;     // 65536

    pack_w_kernel<<<(DIM_O * DIM_D * DIM_K) / 256, 256, 0, stream>>>(coeffs, wp);
    cfkan_kernel<<<n_tokens / BM, 256, 0, stream>>>(x, wp, bias, y);
}